// Round 12
// baseline (283.577 us; speedup 1.0000x reference)
//
#include <hip/hip_runtime.h>
#include <math.h>

#define BB 32
#define AA 8400
#define MM 32
#define NCC 80
#define TOPK 13
#define CAP 1024
#define TILE 128
#define NTILE ((AA + TILE - 1) / TILE)   // 66

typedef float nfloat4 __attribute__((ext_vector_type(4)));   // native vec for nontemporal builtins

// ---------------------------------------------------------------- wave argmax (64-lane, lowest index on tie)
__device__ __forceinline__ void wave_argmax(float& v, int& i) {
    #pragma unroll
    for (int off = 32; off > 0; off >>= 1) {
        float ov = __shfl_xor(v, off, 64);
        int oi = __shfl_xor(i, off, 64);
        if (ov > v || (ov == v && oi < i)) { v = ov; i = oi; }
    }
}

// ---------------------------------------------------------------- K0: zero the per-(b,m) candidate counters
__global__ __launch_bounds__(256) void k0_zero(int* __restrict__ gcnt) {
    int t = threadIdx.x;
    #pragma unroll
    for (int j = 0; j < 4; j++) gcnt[t + j * 256] = 0;
}

// ---------------------------------------------------------------- K1: stream score tiles through LDS, emit positive candidates
__global__ __launch_bounds__(256) void k1_cand(
        const float* __restrict__ pd_scores, const float* __restrict__ pd_bboxes,
        const float* __restrict__ anc, const int* __restrict__ gt_labels,
        const float* __restrict__ gt_bboxes, const float* __restrict__ mask_gt,
        int* __restrict__ gcnt, int2* __restrict__ cand) {
    __shared__ float  ssc[TILE * NCC];     // 40 KB: full score rows for this tile
    __shared__ float4 spb[TILE];
    __shared__ float  sax[TILE], say[TILE], satp[TILE], sw2h2[TILE], sspx[TILE], sspy[TILE];
    __shared__ float  sg[MM][8];           // x1,y1,x2,y2,w1h1,atg,sgx,sgy
    __shared__ int    slab[MM], smg[MM];
    const float eps = 1e-7f;
    int b  = blockIdx.y;
    int a0 = blockIdx.x * TILE;
    int na = min(TILE, AA - a0);
    int tid = threadIdx.x;

    // stage scores (coalesced float4 stream)
    const float4* s4 = reinterpret_cast<const float4*>(pd_scores + ((long)b * AA + a0) * NCC);
    int nq = na * (NCC / 4);
    for (int j = tid; j < nq; j += 256) reinterpret_cast<float4*>(ssc)[j] = s4[j];
    // stage per-anchor data + precompute
    if (tid < na) {
        float4 pb = reinterpret_cast<const float4*>(pd_bboxes)[(long)b * AA + a0 + tid];
        spb[tid] = pb;
        float2 an = reinterpret_cast<const float2*>(anc)[a0 + tid];
        sax[tid] = an.x; say[tid] = an.y;
        float w2 = pb.z - pb.x, h2 = pb.w - pb.y + eps;
        satp[tid]  = atanf(w2 / h2);
        sw2h2[tid] = w2 * h2;
        sspx[tid]  = pb.x + pb.z;
        sspy[tid]  = pb.y + pb.w;
    }
    // stage per-gt data
    if (tid >= 128 && tid < 128 + MM) {
        int m = tid - 128;
        int gm = b * MM + m;
        float4 g = reinterpret_cast<const float4*>(gt_bboxes)[gm];
        float w1 = g.z - g.x, h1 = g.w - g.y + eps;
        sg[m][0] = g.x; sg[m][1] = g.y; sg[m][2] = g.z; sg[m][3] = g.w;
        sg[m][4] = w1 * h1;
        sg[m][5] = atanf(w1 / h1);
        sg[m][6] = g.x + g.z;
        sg[m][7] = g.y + g.w;
        slab[m] = gt_labels[gm];
        smg[m]  = mask_gt[gm] > 0.f ? 1 : 0;
    }
    __syncthreads();

    int npair = na * MM;
    for (int pr = tid; pr < npair; pr += 256) {
        int al = pr >> 5;      // anchor within tile
        int m  = pr & 31;
        if (!smg[m]) continue;
        float ax = sax[al], ay = say[al];
        float gx1 = sg[m][0], gy1 = sg[m][1], gx2 = sg[m][2], gy2 = sg[m][3];
        float dmin = fminf(fminf(ax - gx1, ay - gy1), fminf(gx2 - ax, gy2 - ay));
        if (dmin > 1e-9f) {
            float4 pb = spb[al];
            float iw = fmaxf(fminf(gx2, pb.z) - fmaxf(gx1, pb.x), 0.f);
            float ih = fmaxf(fminf(gy2, pb.w) - fmaxf(gy1, pb.y), 0.f);
            float inter = iw * ih;
            float uni = sg[m][4] + sw2h2[al] - inter + eps;
            float iou = inter / uni;
            float cw = fmaxf(gx2, pb.z) - fminf(gx1, pb.x);
            float ch = fmaxf(gy2, pb.w) - fminf(gy1, pb.y);
            float c2 = cw * cw + ch * ch + eps;
            float dx = sspx[al] - sg[m][6], dy = sspy[al] - sg[m][7];
            float rho2 = (dx * dx + dy * dy) * 0.25f;
            float dv = satp[al] - sg[m][5];
            float v = 0.4052847345693511f * dv * dv;
            float alpha = v / (v - iou + (1.0f + eps));
            float cv = iou - (rho2 / c2 + v * alpha);
            float ov = fmaxf(cv, 0.f);
            if (ov > 0.f) {
                float sc = ssc[al * NCC + slab[m]];
                float o2 = ov * ov;
                float val = sc * o2 * o2 * o2;   // ALPHA=1, BETA=6
                if (val > 0.f) {                 // only positives can ever be selected
                    int bm = b * MM + m;
                    int slot = atomicAdd(&gcnt[bm], 1);
                    if (slot < CAP) cand[(long)bm * CAP + slot] = make_int2(__float_as_int(val), a0 + al);
                }
            }
        }
    }
}

// ---------------------------------------------------------------- K2b: top-13 per (b,m) from its candidate bin
__global__ __launch_bounds__(256) void k2b_topk(
        const int2* __restrict__ cand, const int* __restrict__ gcnt,
        const float* __restrict__ anc, const float* __restrict__ gt_bboxes,
        const float* __restrict__ mask_gt,
        int* __restrict__ sel_idx, float* __restrict__ pos_am, float* __restrict__ pos_ov) {
    __shared__ float wv[4];
    __shared__ int   wi[4];
    __shared__ int   pos_idx[16];
    __shared__ int   s_sel;
    int bm = blockIdx.x;
    int tid = threadIdx.x;
    int lane = tid & 63;
    int wid = tid >> 6;
    if (tid == 0) pos_am[bm] = 0.f;
    if (tid == 1) pos_ov[bm] = 0.f;
    if (tid < 16) sel_idx[bm * 16 + tid] = -1;   // ws poisoned every call; -1 = empty slot
    if (!(mask_gt[bm] > 0.f)) return;  // mg=false row -> no selections

    int n = min(gcnt[bm], CAP);
    const int2* cb = cand + (long)bm * CAP;

    if (n >= TOPK) {
        // 13 extraction rounds, register-resident (4 slots/thread)
        float v0, v1, v2, v3; int i0, i1, i2, i3;
        {
            int s;
            s = tid;       if (s < n) { int2 c = cb[s]; v0 = __int_as_float(c.x); i0 = c.y; } else { v0 = -1.f; i0 = AA; }
            s = tid + 256; if (s < n) { int2 c = cb[s]; v1 = __int_as_float(c.x); i1 = c.y; } else { v1 = -1.f; i1 = AA; }
            s = tid + 512; if (s < n) { int2 c = cb[s]; v2 = __int_as_float(c.x); i2 = c.y; } else { v2 = -1.f; i2 = AA; }
            s = tid + 768; if (s < n) { int2 c = cb[s]; v3 = __int_as_float(c.x); i3 = c.y; } else { v3 = -1.f; i3 = AA; }
        }
        int mysel = -1;
        for (int k = 0; k < TOPK; k++) {
            float bv = v0; int bi = i0;
            if (v1 > bv || (v1 == bv && i1 < bi)) { bv = v1; bi = i1; }
            if (v2 > bv || (v2 == bv && i2 < bi)) { bv = v2; bi = i2; }
            if (v3 > bv || (v3 == bv && i3 < bi)) { bv = v3; bi = i3; }
            wave_argmax(bv, bi);
            if (lane == 0) { wv[wid] = bv; wi[wid] = bi; }
            __syncthreads();
            float gv = wv[0]; int gi = wi[0];
            #pragma unroll
            for (int w = 1; w < 4; w++) {
                float ov = wv[w]; int oi = wi[w];
                if (ov > gv || (ov == gv && oi < gi)) { gv = ov; gi = oi; }
            }
            if (tid == k) mysel = gi;           // thread k owns round-k winner
            if (i0 == gi) v0 = -1.f;            // indices unique: exact ownership
            if (i1 == gi) v1 = -1.f;
            if (i2 == gi) v2 = -1.f;
            if (i3 == gi) v3 = -1.f;
            __syncthreads();
        }
        if (tid < TOPK) sel_idx[bm * 16 + tid] = mysel;
    } else {
        // all n positives selected; remaining 13-n picks = lowest-index NON-positive anchors
        if (tid == 0) s_sel = n;
        if (tid < n) { int2 c = cb[tid]; sel_idx[bm * 16 + tid] = c.y; pos_idx[tid] = c.y; }
        __syncthreads();
        if (wid == 0) {
            float4 g = reinterpret_cast<const float4*>(gt_bboxes)[bm];
            int need = TOPK - n;
            for (int base_i = 0; need > 0 && base_i < AA; base_i += 64) {
                int i = base_i + lane;
                bool candl = (i < AA);
                for (int q = 0; q < n; q++) if (i == pos_idx[q]) candl = false;
                unsigned long long wm = __ballot(candl);
                int take = min(need, (int)__popcll(wm));
                if (candl && (int)__popcll(wm & ((1ull << lane) - 1ull)) < take) {
                    // selected by top_k regardless of in-gts; in-gts mask applies after
                    float2 an = reinterpret_cast<const float2*>(anc)[i];
                    float dmin = fminf(fminf(an.x - g.x, an.y - g.y), fminf(g.z - an.x, g.w - an.y));
                    if (dmin > 1e-9f) {
                        int slot = atomicAdd(&s_sel, 1);
                        sel_idx[bm * 16 + slot] = i;
                    }
                }
                need -= take;
            }
        }
    }
}

// ---------------------------------------------------------------- K3: per-anchor column resolve (mask from sel_idx lists)
__global__ __launch_bounds__(256) void k3_resolve(
        const float* __restrict__ pd_scores, const float* __restrict__ pd_bboxes,
        const float* __restrict__ anc, const int* __restrict__ gt_labels,
        const float* __restrict__ gt_bboxes, const float* __restrict__ mask_gt,
        const int* __restrict__ sel_idx,
        float* __restrict__ pos_am, float* __restrict__ pos_ov,
        float* __restrict__ out_bbox, float* __restrict__ out_fg,
        int2* __restrict__ meta) {
    __shared__ float sg[MM][8];
    __shared__ int slab[MM];
    __shared__ int smg[MM];
    __shared__ unsigned int selcol[256];
    const float eps = 1e-7f;
    int b = blockIdx.y;
    int tid = threadIdx.x;
    if (tid < MM) {
        int gm = b * MM + tid;
        float4 g = reinterpret_cast<const float4*>(gt_bboxes)[gm];
        float w1 = g.z - g.x, h1 = g.w - g.y + eps;
        sg[tid][0] = g.x; sg[tid][1] = g.y; sg[tid][2] = g.z; sg[tid][3] = g.w;
        sg[tid][4] = w1 * h1;
        sg[tid][5] = atanf(w1 / h1);
        sg[tid][6] = g.x + g.z;
        sg[tid][7] = g.y + g.w;
        int lb = gt_labels[gm]; if (lb < 0) lb = 0;
        slab[tid] = lb;
        smg[tid] = mask_gt[gm] > 0.f ? 1 : 0;
    }
    selcol[tid] = 0u;
    __syncthreads();
    int a0 = blockIdx.x * 256;
    const int* sl = sel_idx + b * MM * 16;
    #pragma unroll
    for (int t = tid; t < MM * 16; t += 256) {
        int e = sl[t];
        if (e >= a0 && e < a0 + 256) atomicOr(&selcol[e - a0], 1u << (t >> 4));
    }
    __syncthreads();
    int a = a0 + tid;
    if (a >= AA) return;
    int g = b * AA + a;
    unsigned int sel = selcol[tid];
    int fg = __popc(sel);

    int tg = 0; bool fgo = false; float ovt = 0.f;
    if (fg >= 1) {
        float ax = anc[a * 2], ay = anc[a * 2 + 1];
        float4 pb = reinterpret_cast<const float4*>(pd_bboxes)[g];
        float w2 = pb.z - pb.x, h2 = pb.w - pb.y + eps;
        float atp = atanf(w2 / h2);
        float w2h2 = w2 * h2;
        float spx = pb.x + pb.z, spy = pb.y + pb.w;
        fgo = true;
        if (fg == 1) {
            tg = __ffs(sel) - 1;
            float gx1 = sg[tg][0], gy1 = sg[tg][1], gx2 = sg[tg][2], gy2 = sg[tg][3];
            float iw = fmaxf(fminf(gx2, pb.z) - fmaxf(gx1, pb.x), 0.f);
            float ih = fmaxf(fminf(gy2, pb.w) - fmaxf(gy1, pb.y), 0.f);
            float inter = iw * ih;
            float uni = sg[tg][4] + w2h2 - inter + eps;
            float iou = inter / uni;
            float cw = fmaxf(gx2, pb.z) - fminf(gx1, pb.x);
            float ch = fmaxf(gy2, pb.w) - fminf(gy1, pb.y);
            float c2 = cw * cw + ch * ch + eps;
            float dx = spx - sg[tg][6], dy = spy - sg[tg][7];
            float rho2 = (dx * dx + dy * dy) * 0.25f;
            float dv = atp - sg[tg][5];
            float v = 0.4052847345693511f * dv * dv;
            float alpha = v / (v - iou + (1.0f + eps));
            ovt = fmaxf(iou - (rho2 / c2 + v * alpha), 0.f);
        } else {
            float bestov = -1.f; int bestm = 0;
            for (int mm = 0; mm < MM; mm++) {
                float gx1 = sg[mm][0], gy1 = sg[mm][1], gx2 = sg[mm][2], gy2 = sg[mm][3];
                float dmin = fminf(fminf(ax - gx1, ay - gy1), fminf(gx2 - ax, gy2 - ay));
                float ov = 0.f;
                if ((dmin > 1e-9f) && smg[mm]) {
                    float iw = fmaxf(fminf(gx2, pb.z) - fmaxf(gx1, pb.x), 0.f);
                    float ih = fmaxf(fminf(gy2, pb.w) - fmaxf(gy1, pb.y), 0.f);
                    float inter = iw * ih;
                    float uni = sg[mm][4] + w2h2 - inter + eps;
                    float iou = inter / uni;
                    float cw = fmaxf(gx2, pb.z) - fminf(gx1, pb.x);
                    float ch = fmaxf(gy2, pb.w) - fminf(gy1, pb.y);
                    float c2 = cw * cw + ch * ch + eps;
                    float dx = spx - sg[mm][6], dy = spy - sg[mm][7];
                    float rho2 = (dx * dx + dy * dy) * 0.25f;
                    float dv = atp - sg[mm][5];
                    float v = 0.4052847345693511f * dv * dv;
                    float alpha = v / (v - iou + (1.0f + eps));
                    ov = fmaxf(iou - (rho2 / c2 + v * alpha), 0.f);
                }
                if (ov > bestov) { bestov = ov; bestm = mm; }
            }
            tg = bestm; ovt = bestov;
        }
    }

    nfloat4 gb = {sg[tg][0], sg[tg][1], sg[tg][2], sg[tg][3]};
    __builtin_nontemporal_store(gb, reinterpret_cast<nfloat4*>(out_bbox) + g);
    out_fg[g] = fgo ? 1.f : 0.f;
    float amv = 0.f;
    if (fgo) {
        float sc = pd_scores[(long)g * NCC + slab[tg]];
        float o2 = ovt * ovt;
        amv = sc * o2 * o2 * o2;
        atomicMax((int*)&pos_am[b * MM + tg], __float_as_int(amv));   // non-negative floats: int order == float order
        atomicMax((int*)&pos_ov[b * MM + tg], __float_as_int(ovt));
    }
    meta[g] = make_int2(__float_as_int(amv), tg | (slab[tg] << 8) | ((fgo ? 1 : 0) << 16));
}

// ---------------------------------------------------------------- K4: norm + one-hot target_scores (nontemporal float4)
__global__ __launch_bounds__(256) void k4_scores(
        const int2* __restrict__ meta,
        const float* __restrict__ pos_am, const float* __restrict__ pos_ov,
        float* __restrict__ out_scores) {
    int g = blockIdx.x * 256 + threadIdx.x;
    const int NQ = NCC / 4;
    if (g >= BB * AA * NQ) return;
    int ba = g / NQ;
    int c0 = (g % NQ) * 4;
    nfloat4 o = {0.f, 0.f, 0.f, 0.f};
    int2 mt = meta[ba];
    int p = mt.y;
    if (p & (1 << 16)) {
        int tg = p & 31, lab = (p >> 8) & 127;
        int b = ba / AA;
        int bm = b * MM + tg;
        float nv = (__int_as_float(mt.x) * pos_ov[bm]) / (pos_am[bm] + 1e-9f);
        int d = lab - c0;
        if (d == 0) o.x = nv; else if (d == 1) o.y = nv;
        else if (d == 2) o.z = nv; else if (d == 3) o.w = nv;
    }
    __builtin_nontemporal_store(o, reinterpret_cast<nfloat4*>(out_scores) + g);
}

// ---------------------------------------------------------------- launch
extern "C" void kernel_launch(void* const* d_in, const int* in_sizes, int n_in,
                              void* d_out, int out_size, void* d_ws, size_t ws_size,
                              hipStream_t stream) {
    const float* pd_scores = (const float*)d_in[0];
    const float* pd_bboxes = (const float*)d_in[1];
    const float* anc       = (const float*)d_in[2];
    const int*   gt_labels = (const int*)d_in[3];
    const float* gt_bboxes = (const float*)d_in[4];
    const float* mask_gt   = (const float*)d_in[5];

    const long nBA = (long)BB * AA;
    const long nBM = (long)BB * MM;   // 1024

    char* ws = (char*)d_ws;
    int2*  cand    = (int2*)ws;                 ws += nBM * CAP * 8;   // 8 MB
    int2*  meta    = (int2*)ws;                 ws += nBA * 8;         // 2.1 MB
    int*   gcnt    = (int*)ws;                  ws += nBM * 4;
    int*   sel_idx = (int*)ws;                  ws += nBM * 16 * 4;
    float* pos_am  = (float*)ws;                ws += nBM * 4;
    float* pos_ov  = (float*)ws;                ws += nBM * 4;

    float* out_bbox   = (float*)d_out;            // B*A*4
    float* out_scores = out_bbox + nBA * 4;       // B*A*NC
    float* out_fg     = out_scores + nBA * NCC;   // B*A

    k0_zero<<<1, 256, 0, stream>>>(gcnt);
    dim3 g1(NTILE, BB);
    k1_cand<<<g1, 256, 0, stream>>>(pd_scores, pd_bboxes, anc, gt_labels,
                                    gt_bboxes, mask_gt, gcnt, cand);
    k2b_topk<<<(int)nBM, 256, 0, stream>>>(cand, gcnt, anc, gt_bboxes, mask_gt,
                                           sel_idx, pos_am, pos_ov);
    dim3 g3((AA + 255) / 256, BB);
    k3_resolve<<<g3, 256, 0, stream>>>(pd_scores, pd_bboxes, anc, gt_labels,
                                       gt_bboxes, mask_gt, sel_idx, pos_am, pos_ov,
                                       out_bbox, out_fg, meta);
    long nS4 = nBA * (NCC / 4);
    k4_scores<<<(int)((nS4 + 255) / 256), 256, 0, stream>>>(meta, pos_am, pos_ov, out_scores);
}

// Round 13
// 282.866 us; speedup vs baseline: 1.0025x; 1.0025x over previous
//
#include <hip/hip_runtime.h>
#include <math.h>

#define BB 32
#define AA 8400
#define MM 32
#define NCC 80
#define TOPK 13
#define CAP 1024

typedef float nfloat4 __attribute__((ext_vector_type(4)));   // native vec for nontemporal builtins

// ---------------------------------------------------------------- wave argmax (64-lane, lowest index on tie)
__device__ __forceinline__ void wave_argmax(float& v, int& i) {
    #pragma unroll
    for (int off = 32; off > 0; off >>= 1) {
        float ov = __shfl_xor(v, off, 64);
        int oi = __shfl_xor(i, off, 64);
        if (ov > v || (ov == v && oi < i)) { v = ov; i = oi; }
    }
}

// ---------------------------------------------------------------- K0: zero the per-(b,m) candidate counters
__global__ __launch_bounds__(256) void k0_zero(int* __restrict__ gcnt) {
    int t = threadIdx.x;
    #pragma unroll
    for (int j = 0; j < 4; j++) gcnt[t + j * 256] = 0;
}

// ---------------------------------------------------------------- K1: max-TLP candidate emission (no LDS, no barriers)
// one thread per (anchor, gt): only ~3% of threads reach the gather; all gathers fly concurrently
__global__ __launch_bounds__(256) void k1_cand(
        const float* __restrict__ pd_scores, const float* __restrict__ pd_bboxes,
        const float* __restrict__ anc, const int* __restrict__ gt_labels,
        const float* __restrict__ gt_bboxes, const float* __restrict__ mask_gt,
        int* __restrict__ gcnt, int2* __restrict__ cand) {
    const float eps = 1e-7f;
    int bm = blockIdx.y;                  // (b,m), wave-uniform
    if (!(mask_gt[bm] > 0.f)) return;     // scalar test, half the blocks exit immediately
    int b = bm >> 5;
    int i = blockIdx.x * 256 + threadIdx.x;
    if (i >= AA) return;
    float4 g = reinterpret_cast<const float4*>(gt_bboxes)[bm];   // scalar (uniform)
    float2 an = reinterpret_cast<const float2*>(anc)[i];         // L2-resident, coalesced
    float dmin = fminf(fminf(an.x - g.x, an.y - g.y), fminf(g.z - an.x, g.w - an.y));
    if (dmin <= 1e-9f) return;

    float4 pb = reinterpret_cast<const float4*>(pd_bboxes)[(long)b * AA + i];
    int lab = gt_labels[bm];                                     // scalar
    float sc = pd_scores[((long)b * AA + i) * NCC + lab];        // THE scatter — hidden by TLP
    float w1 = g.z - g.x, h1 = g.w - g.y + eps;
    float w2 = pb.z - pb.x, h2 = pb.w - pb.y + eps;
    float iw = fmaxf(fminf(g.z, pb.z) - fmaxf(g.x, pb.x), 0.f);
    float ih = fmaxf(fminf(g.w, pb.w) - fmaxf(g.y, pb.y), 0.f);
    float inter = iw * ih;
    float uni = w1 * h1 + w2 * h2 - inter + eps;
    float iou = inter / uni;
    float cw = fmaxf(g.z, pb.z) - fminf(g.x, pb.x);
    float ch = fmaxf(g.w, pb.w) - fminf(g.y, pb.y);
    float c2 = cw * cw + ch * ch + eps;
    float dx = pb.x + pb.z - g.x - g.z, dy = pb.y + pb.w - g.y - g.w;
    float rho2 = (dx * dx + dy * dy) * 0.25f;
    float dv = atanf(w2 / h2) - atanf(w1 / h1);
    float v = 0.4052847345693511f * dv * dv;
    float alpha = v / (v - iou + (1.0f + eps));
    float cv = iou - (rho2 / c2 + v * alpha);
    float ov = fmaxf(cv, 0.f);
    float o2 = ov * ov;
    float val = sc * o2 * o2 * o2;        // ALPHA=1, BETA=6
    if (val > 0.f) {                      // only positives can ever be selected
        int slot = atomicAdd(&gcnt[bm], 1);
        if (slot < CAP) cand[(long)bm * CAP + slot] = make_int2(__float_as_int(val), i);
    }
}

// ---------------------------------------------------------------- K2b: top-13 per (b,m) from its candidate bin
__global__ __launch_bounds__(256) void k2b_topk(
        const int2* __restrict__ cand, const int* __restrict__ gcnt,
        const float* __restrict__ anc, const float* __restrict__ gt_bboxes,
        const float* __restrict__ mask_gt,
        int* __restrict__ sel_idx, float* __restrict__ pos_am, float* __restrict__ pos_ov) {
    __shared__ float wv[4];
    __shared__ int   wi[4];
    __shared__ int   pos_idx[16];
    __shared__ int   s_sel;
    int bm = blockIdx.x;
    int tid = threadIdx.x;
    int lane = tid & 63;
    int wid = tid >> 6;
    if (tid == 0) pos_am[bm] = 0.f;
    if (tid == 1) pos_ov[bm] = 0.f;
    if (tid < 16) sel_idx[bm * 16 + tid] = -1;   // ws poisoned every call; -1 = empty slot
    if (!(mask_gt[bm] > 0.f)) return;  // mg=false row -> no selections

    int n = min(gcnt[bm], CAP);
    const int2* cb = cand + (long)bm * CAP;

    if (n >= TOPK) {
        // 13 extraction rounds, register-resident (4 slots/thread)
        float v0, v1, v2, v3; int i0, i1, i2, i3;
        {
            int s;
            s = tid;       if (s < n) { int2 c = cb[s]; v0 = __int_as_float(c.x); i0 = c.y; } else { v0 = -1.f; i0 = AA; }
            s = tid + 256; if (s < n) { int2 c = cb[s]; v1 = __int_as_float(c.x); i1 = c.y; } else { v1 = -1.f; i1 = AA; }
            s = tid + 512; if (s < n) { int2 c = cb[s]; v2 = __int_as_float(c.x); i2 = c.y; } else { v2 = -1.f; i2 = AA; }
            s = tid + 768; if (s < n) { int2 c = cb[s]; v3 = __int_as_float(c.x); i3 = c.y; } else { v3 = -1.f; i3 = AA; }
        }
        int mysel = -1;
        for (int k = 0; k < TOPK; k++) {
            float bv = v0; int bi = i0;
            if (v1 > bv || (v1 == bv && i1 < bi)) { bv = v1; bi = i1; }
            if (v2 > bv || (v2 == bv && i2 < bi)) { bv = v2; bi = i2; }
            if (v3 > bv || (v3 == bv && i3 < bi)) { bv = v3; bi = i3; }
            wave_argmax(bv, bi);
            if (lane == 0) { wv[wid] = bv; wi[wid] = bi; }
            __syncthreads();
            float gv = wv[0]; int gi = wi[0];
            #pragma unroll
            for (int w = 1; w < 4; w++) {
                float ov = wv[w]; int oi = wi[w];
                if (ov > gv || (ov == gv && oi < gi)) { gv = ov; gi = oi; }
            }
            if (tid == k) mysel = gi;           // thread k owns round-k winner
            if (i0 == gi) v0 = -1.f;            // indices unique: exact ownership
            if (i1 == gi) v1 = -1.f;
            if (i2 == gi) v2 = -1.f;
            if (i3 == gi) v3 = -1.f;
            __syncthreads();
        }
        if (tid < TOPK) sel_idx[bm * 16 + tid] = mysel;
    } else {
        // all n positives selected; remaining 13-n picks = lowest-index NON-positive anchors
        if (tid == 0) s_sel = n;
        if (tid < n) { int2 c = cb[tid]; sel_idx[bm * 16 + tid] = c.y; pos_idx[tid] = c.y; }
        __syncthreads();
        if (wid == 0) {
            float4 g = reinterpret_cast<const float4*>(gt_bboxes)[bm];
            int need = TOPK - n;
            for (int base_i = 0; need > 0 && base_i < AA; base_i += 64) {
                int i = base_i + lane;
                bool candl = (i < AA);
                for (int q = 0; q < n; q++) if (i == pos_idx[q]) candl = false;
                unsigned long long wm = __ballot(candl);
                int take = min(need, (int)__popcll(wm));
                if (candl && (int)__popcll(wm & ((1ull << lane) - 1ull)) < take) {
                    // selected by top_k regardless of in-gts; in-gts mask applies after
                    float2 an = reinterpret_cast<const float2*>(anc)[i];
                    float dmin = fminf(fminf(an.x - g.x, an.y - g.y), fminf(g.z - an.x, g.w - an.y));
                    if (dmin > 1e-9f) {
                        int slot = atomicAdd(&s_sel, 1);
                        sel_idx[bm * 16 + slot] = i;
                    }
                }
                need -= take;
            }
        }
    }
}

// ---------------------------------------------------------------- K3: per-anchor column resolve (mask from sel_idx lists)
__global__ __launch_bounds__(256) void k3_resolve(
        const float* __restrict__ pd_scores, const float* __restrict__ pd_bboxes,
        const float* __restrict__ anc, const int* __restrict__ gt_labels,
        const float* __restrict__ gt_bboxes, const float* __restrict__ mask_gt,
        const int* __restrict__ sel_idx,
        float* __restrict__ pos_am, float* __restrict__ pos_ov,
        float* __restrict__ out_bbox, float* __restrict__ out_fg,
        int2* __restrict__ meta) {
    __shared__ float sg[MM][8];
    __shared__ int slab[MM];
    __shared__ int smg[MM];
    __shared__ unsigned int selcol[256];
    const float eps = 1e-7f;
    int b = blockIdx.y;
    int tid = threadIdx.x;
    if (tid < MM) {
        int gm = b * MM + tid;
        float4 g = reinterpret_cast<const float4*>(gt_bboxes)[gm];
        float w1 = g.z - g.x, h1 = g.w - g.y + eps;
        sg[tid][0] = g.x; sg[tid][1] = g.y; sg[tid][2] = g.z; sg[tid][3] = g.w;
        sg[tid][4] = w1 * h1;
        sg[tid][5] = atanf(w1 / h1);
        sg[tid][6] = g.x + g.z;
        sg[tid][7] = g.y + g.w;
        int lb = gt_labels[gm]; if (lb < 0) lb = 0;
        slab[tid] = lb;
        smg[tid] = mask_gt[gm] > 0.f ? 1 : 0;
    }
    selcol[tid] = 0u;
    __syncthreads();
    int a0 = blockIdx.x * 256;
    const int* sl = sel_idx + b * MM * 16;
    #pragma unroll
    for (int t = tid; t < MM * 16; t += 256) {
        int e = sl[t];
        if (e >= a0 && e < a0 + 256) atomicOr(&selcol[e - a0], 1u << (t >> 4));
    }
    __syncthreads();
    int a = a0 + tid;
    if (a >= AA) return;
    int g = b * AA + a;
    unsigned int sel = selcol[tid];
    int fg = __popc(sel);

    int tg = 0; bool fgo = false; float ovt = 0.f;
    if (fg >= 1) {
        float ax = anc[a * 2], ay = anc[a * 2 + 1];
        float4 pb = reinterpret_cast<const float4*>(pd_bboxes)[g];
        float w2 = pb.z - pb.x, h2 = pb.w - pb.y + eps;
        float atp = atanf(w2 / h2);
        float w2h2 = w2 * h2;
        float spx = pb.x + pb.z, spy = pb.y + pb.w;
        fgo = true;
        if (fg == 1) {
            tg = __ffs(sel) - 1;
            float gx1 = sg[tg][0], gy1 = sg[tg][1], gx2 = sg[tg][2], gy2 = sg[tg][3];
            float iw = fmaxf(fminf(gx2, pb.z) - fmaxf(gx1, pb.x), 0.f);
            float ih = fmaxf(fminf(gy2, pb.w) - fmaxf(gy1, pb.y), 0.f);
            float inter = iw * ih;
            float uni = sg[tg][4] + w2h2 - inter + eps;
            float iou = inter / uni;
            float cw = fmaxf(gx2, pb.z) - fminf(gx1, pb.x);
            float ch = fmaxf(gy2, pb.w) - fminf(gy1, pb.y);
            float c2 = cw * cw + ch * ch + eps;
            float dx = spx - sg[tg][6], dy = spy - sg[tg][7];
            float rho2 = (dx * dx + dy * dy) * 0.25f;
            float dv = atp - sg[tg][5];
            float v = 0.4052847345693511f * dv * dv;
            float alpha = v / (v - iou + (1.0f + eps));
            ovt = fmaxf(iou - (rho2 / c2 + v * alpha), 0.f);
        } else {
            float bestov = -1.f; int bestm = 0;
            for (int mm = 0; mm < MM; mm++) {
                float gx1 = sg[mm][0], gy1 = sg[mm][1], gx2 = sg[mm][2], gy2 = sg[mm][3];
                float dmin = fminf(fminf(ax - gx1, ay - gy1), fminf(gx2 - ax, gy2 - ay));
                float ov = 0.f;
                if ((dmin > 1e-9f) && smg[mm]) {
                    float iw = fmaxf(fminf(gx2, pb.z) - fmaxf(gx1, pb.x), 0.f);
                    float ih = fmaxf(fminf(gy2, pb.w) - fmaxf(gy1, pb.y), 0.f);
                    float inter = iw * ih;
                    float uni = sg[mm][4] + w2h2 - inter + eps;
                    float iou = inter / uni;
                    float cw = fmaxf(gx2, pb.z) - fminf(gx1, pb.x);
                    float ch = fmaxf(gy2, pb.w) - fminf(gy1, pb.y);
                    float c2 = cw * cw + ch * ch + eps;
                    float dx = spx - sg[mm][6], dy = spy - sg[mm][7];
                    float rho2 = (dx * dx + dy * dy) * 0.25f;
                    float dv = atp - sg[mm][5];
                    float v = 0.4052847345693511f * dv * dv;
                    float alpha = v / (v - iou + (1.0f + eps));
                    ov = fmaxf(iou - (rho2 / c2 + v * alpha), 0.f);
                }
                if (ov > bestov) { bestov = ov; bestm = mm; }
            }
            tg = bestm; ovt = bestov;
        }
    }

    nfloat4 gb = {sg[tg][0], sg[tg][1], sg[tg][2], sg[tg][3]};
    __builtin_nontemporal_store(gb, reinterpret_cast<nfloat4*>(out_bbox) + g);
    out_fg[g] = fgo ? 1.f : 0.f;
    float amv = 0.f;
    if (fgo) {
        float sc = pd_scores[(long)g * NCC + slab[tg]];
        float o2 = ovt * ovt;
        amv = sc * o2 * o2 * o2;
        atomicMax((int*)&pos_am[b * MM + tg], __float_as_int(amv));   // non-negative floats: int order == float order
        atomicMax((int*)&pos_ov[b * MM + tg], __float_as_int(ovt));
    }
    meta[g] = make_int2(__float_as_int(amv), tg | (slab[tg] << 8) | ((fgo ? 1 : 0) << 16));
}

// ---------------------------------------------------------------- K4: norm + one-hot target_scores (nontemporal float4)
__global__ __launch_bounds__(256) void k4_scores(
        const int2* __restrict__ meta,
        const float* __restrict__ pos_am, const float* __restrict__ pos_ov,
        float* __restrict__ out_scores) {
    int g = blockIdx.x * 256 + threadIdx.x;
    const int NQ = NCC / 4;
    if (g >= BB * AA * NQ) return;
    int ba = g / NQ;
    int c0 = (g % NQ) * 4;
    nfloat4 o = {0.f, 0.f, 0.f, 0.f};
    int2 mt = meta[ba];
    int p = mt.y;
    if (p & (1 << 16)) {
        int tg = p & 31, lab = (p >> 8) & 127;
        int b = ba / AA;
        int bm = b * MM + tg;
        float nv = (__int_as_float(mt.x) * pos_ov[bm]) / (pos_am[bm] + 1e-9f);
        int d = lab - c0;
        if (d == 0) o.x = nv; else if (d == 1) o.y = nv;
        else if (d == 2) o.z = nv; else if (d == 3) o.w = nv;
    }
    __builtin_nontemporal_store(o, reinterpret_cast<nfloat4*>(out_scores) + g);
}

// ---------------------------------------------------------------- launch
extern "C" void kernel_launch(void* const* d_in, const int* in_sizes, int n_in,
                              void* d_out, int out_size, void* d_ws, size_t ws_size,
                              hipStream_t stream) {
    const float* pd_scores = (const float*)d_in[0];
    const float* pd_bboxes = (const float*)d_in[1];
    const float* anc       = (const float*)d_in[2];
    const int*   gt_labels = (const int*)d_in[3];
    const float* gt_bboxes = (const float*)d_in[4];
    const float* mask_gt   = (const float*)d_in[5];

    const long nBA = (long)BB * AA;
    const long nBM = (long)BB * MM;   // 1024

    char* ws = (char*)d_ws;
    int2*  cand    = (int2*)ws;                 ws += nBM * CAP * 8;   // 8 MB
    int2*  meta    = (int2*)ws;                 ws += nBA * 8;         // 2.1 MB
    int*   gcnt    = (int*)ws;                  ws += nBM * 4;
    int*   sel_idx = (int*)ws;                  ws += nBM * 16 * 4;
    float* pos_am  = (float*)ws;                ws += nBM * 4;
    float* pos_ov  = (float*)ws;                ws += nBM * 4;

    float* out_bbox   = (float*)d_out;            // B*A*4
    float* out_scores = out_bbox + nBA * 4;       // B*A*NC
    float* out_fg     = out_scores + nBA * NCC;   // B*A

    k0_zero<<<1, 256, 0, stream>>>(gcnt);
    dim3 g1((AA + 255) / 256, (int)nBM);          // 33 x 1024 micro-blocks: max TLP for the gather
    k1_cand<<<g1, 256, 0, stream>>>(pd_scores, pd_bboxes, anc, gt_labels,
                                    gt_bboxes, mask_gt, gcnt, cand);
    k2b_topk<<<(int)nBM, 256, 0, stream>>>(cand, gcnt, anc, gt_bboxes, mask_gt,
                                           sel_idx, pos_am, pos_ov);
    dim3 g3((AA + 255) / 256, BB);
    k3_resolve<<<g3, 256, 0, stream>>>(pd_scores, pd_bboxes, anc, gt_labels,
                                       gt_bboxes, mask_gt, sel_idx, pos_am, pos_ov,
                                       out_bbox, out_fg, meta);
    long nS4 = nBA * (NCC / 4);
    k4_scores<<<(int)((nS4 + 255) / 256), 256, 0, stream>>>(meta, pos_am, pos_ov, out_scores);
}